// Round 8
// baseline (317.198 us; speedup 1.0000x reference)
//
#include <hip/hip_runtime.h>

// CharBiLSTMEmbedder: N=32768 words, T=20, E=H=50, V=200, out [N,100] fp32.
//
// Round-14: BARRIER-FREE step loop. Rounds 2/4/5/7 all bound ~69-78us by the
// per-step __syncthreads (tiles split across waves => shared h dbuf). Fix:
// one wave owns ALL 13 tiles of its own 16-word group; h is wave-private LDS
// (single-buffered; same-wave in-order DS ops + lgkmcnt make read-after-write
// safe). Block = 256 thr = 4 independent waves sharing only the staged Whh
// A-image (26.6KB LDS). No __syncthreads after staging. 16 waves/CU
// (LDS-capped, occupancy reads ~50% - expected); 4 decorrelated waves/SIMD.
// This is round-0's structure minus its two defects: G now bf16-from-L2
// (round-2 win) and chars pre-multiplied (round-10 win).
// Carried: exp2-domain gates (scales baked into G/W images), counting-sort
// LPT order, k_prep LDS-staged Wih, 3 plain launches.

#define TT    20
#define HH    50
#define VV    200
#define TILES 13        // 13*16 = 208 rows >= 200
#define GSTR  212       // G row stride in shorts (53 units * 4 gates)
#define GSH   (VV * GSTR)        // 42400 shorts per dir
#define WSH   (TILES * 16 * 64)  // 13312 shorts per dir
#define NW    32768
#define NB_G  50        // 2 dirs * 25 blocks of 8 emb rows
#define NB_W  104       // ceil(2*WSH/256)
#define NB_H  128       // 128*256 = 32768 words
#define NBLK  1024      // 2 dirs * 512 four-group clusters

#define N2LOG2E (-1.4426950408889634f)
#define P2LOG2E 2.8853900817779268f

typedef __attribute__((ext_vector_type(8))) short bf16x8;
typedef __attribute__((ext_vector_type(4))) float f32x4;

__device__ __forceinline__ float frcp(float x) { return __builtin_amdgcn_rcpf(x); }
#if __has_builtin(__builtin_amdgcn_exp2f)
__device__ __forceinline__ float fexp2(float x) { return __builtin_amdgcn_exp2f(x); }
#else
__device__ __forceinline__ float fexp2(float x) { return exp2f(x); }
#endif

__device__ __forceinline__ short f2bf(float x) {  // RNE fp32 -> bf16
    unsigned b = __builtin_bit_cast(unsigned, x);
    unsigned r = (b + 0x7FFFu + ((b >> 16) & 1u)) >> 16;
    return (short)r;
}
__device__ __forceinline__ float bfhi(unsigned w) {   // high bf16 of dword
    return __builtin_bit_cast(float, w & 0xFFFF0000u);
}
__device__ __forceinline__ float bflo(unsigned w) {   // low bf16 of dword
    return __builtin_bit_cast(float, w << 16);
}

// One kernel, three jobs by block range:
//  [0,NB_G): Gimg[d][v*GSTR+u*4+g] = bf16(sc_g*(emb'[v].W_ih[g*50+u]+b_ih+b_hh))
//            (Wih staged in LDS with sc folded; emb reads wave-uniform)
//  [NB_G,NB_G+NB_W): Wimg = MFMA A-operand image of sc_g*Whh (bf16, k-swizzled)
//  [NB_G+NB_W, +NB_H): cnt[block][21] = length histogram of 256 words
//  sc_g = -log2e for i,f,o rows; +2log2e for g rows (exp2-domain gates).
__global__ void k_prep(const float* __restrict__ emb,
                       const float* __restrict__ Wih_f, const float* __restrict__ bih_f,
                       const float* __restrict__ bhh_f,
                       const float* __restrict__ Wih_b, const float* __restrict__ bih_b,
                       const float* __restrict__ bhh_b,
                       const float* __restrict__ Whh_f, const float* __restrict__ Whh_b,
                       const int* __restrict__ lens,
                       short* __restrict__ Gimg, short* __restrict__ Wimg,
                       int* __restrict__ cnt) {
    int blk = blockIdx.x;
    int tid = threadIdx.x;
    __shared__ float Wl[4 * HH * HH];    // 200x50 f32, pre-scaled (40000 B)
    __shared__ float bs[4 * HH];         // (b_ih+b_hh)*sc

    if (blk < NB_G) {
        int d = blk / 25;
        int vbase = (blk % 25) * 8;
        const float* Wih = d ? Wih_b : Wih_f;
        const float* bih = d ? bih_b : bih_f;
        const float* bhh = d ? bhh_b : bhh_f;
        for (int i = tid; i < 4 * HH * HH; i += 256) {
            int r = i / HH;
            float sc = (r / HH == 2) ? P2LOG2E : N2LOG2E;
            Wl[i] = Wih[i] * sc;
        }
        if (tid < 4 * HH) {
            float sc = (tid / HH == 2) ? P2LOG2E : N2LOG2E;
            bs[tid] = (bih[tid] + bhh[tid]) * sc;
        }
        __syncthreads();
        int r = tid;                      // gate-row 0..199
        if (r < 4 * HH) {
            int g = r / HH, u = r % HH;
            #pragma unroll
            for (int vv = 0; vv < 8; ++vv) {
                int v = vbase + vv;
                float s = bs[r];
                if (v != 0) {             // PAD row of emb is zero
                    #pragma unroll 10
                    for (int e = 0; e < HH; ++e)
                        s = fmaf(emb[v * HH + e], Wl[r * HH + e], s);
                }
                Gimg[d * GSH + v * GSTR + u * 4 + g] = f2bf(s);
            }
        } else {                          // zero pad units u=50..52 (12 shorts/v)
            for (int k = r - 4 * HH; k < 8 * 12; k += 56) {
                int v = vbase + k / 12;
                Gimg[d * GSH + v * GSTR + 4 * HH + (k % 12)] = 0;
            }
        }
    } else if (blk < NB_G + NB_W) {
        int idx = (blk - NB_G) * 256 + tid;
        if (idx >= 2 * WSH) return;
        int d = idx / WSH;
        int e = idx % WSH;
        int t = e >> 10, m = (e >> 6) & 15, k = e & 63;
        int u = 4 * t + (m >> 2), g = m & 3;
        const float* Whh = d ? Whh_b : Whh_f;
        float sc = (g == 2) ? P2LOG2E : N2LOG2E;
        float val = (k < HH && u < HH) ? Whh[(g * HH + u) * HH + k] * sc : 0.0f;
        int ksw = (k & 7) | (((k >> 3) ^ (m & 7)) << 3);
        Wimg[d * WSH + (e & ~63) + ksw] = f2bf(val);
    } else {
        int hb = blk - NB_G - NB_W;      // 0..127
        __shared__ int hcnt[21];
        if (tid < 21) hcnt[tid] = 0;
        __syncthreads();
        atomicAdd(&hcnt[lens[hb * 256 + tid]], 1);
        __syncthreads();
        if (tid < 21) cnt[hb * 21 + tid] = hcnt[tid];
    }
}

// Merged scan+scatter: every block stages the 128x21 histogram into LDS,
// computes its own bucket offsets (buckets ordered L=20..0, LPT), scatters
// its 256 words.
__global__ void k_scat(const int* __restrict__ lens, const int* __restrict__ cnt,
                       int* __restrict__ perm) {
    __shared__ int lcnt[NB_H * 21];     // 10752 B
    __shared__ int part[8][21];
    __shared__ int tot[21];
    __shared__ int cur[21];
    int b = blockIdx.x, t = threadIdx.x;
    for (int i = t; i < NB_H * 21; i += 256) lcnt[i] = cnt[i];
    __syncthreads();
    if (t < 168) {
        int L = t % 21, c = t / 21;
        int s = 0;
        for (int bb = c * 16; bb < c * 16 + 16; ++bb) s += lcnt[bb * 21 + L];
        part[c][L] = s;
    }
    __syncthreads();
    if (t < 21) {
        int a = 0;
        #pragma unroll
        for (int c = 0; c < 8; ++c) a += part[c][t];
        tot[t] = a;
    }
    __syncthreads();
    if (t < 21) {
        int a = 0;
        for (int L2 = 20; L2 > t; --L2) a += tot[L2];   // start of bucket t
        for (int bb = 0; bb < b; ++bb) a += lcnt[bb * 21 + t];
        cur[t] = a;
    }
    __syncthreads();
    int i = b * 256 + t;
    int pos = atomicAdd(&cur[lens[i]], 1);
    perm[pos] = i;
}

// Block = 4 INDEPENDENT waves; each wave = one 16-word group x all 13 tiles.
// h wave-private single-buffered LDS (in-order same-wave DS => no barrier).
// A-image shared in LDS (read-only after staging). G bf16 from L2 per step.
__launch_bounds__(256, 4)
__global__ void k_lstm(const int* __restrict__ chars, const int* __restrict__ lens,
                       const int* __restrict__ perm,
                       const short* __restrict__ Gimg, const short* __restrict__ Wimg,
                       float* __restrict__ out) {
    __shared__ __align__(16) short Wa[WSH];        // 26624 B (one dir A-image)
    __shared__ __align__(16) short hs[4][1024];    // 8192 B wave-private h
    __shared__ unsigned short cs[4 * 16 * TT];     // 2560 B char*GSTR offsets

    int gb   = blockIdx.x;             // 0..1023, LPT (longest clusters first)
    int d    = gb & 1;
    int g4   = gb >> 1;                // 0..511: cluster of 4 sorted groups
    int slot0 = g4 * 64;
    int tid  = threadIdx.x;            // 0..255
    int lane = tid & 63;
    int wv   = __builtin_amdgcn_readfirstlane(tid >> 6);   // 0..3
    int quad = lane >> 4;
    int n    = lane & 15;
    int x7   = n & 7;

    // ---- stage (the only barrier in the kernel is after this) ----
    {
        const int4* src = (const int4*)(Wimg + d * WSH);
        int4* dst = (int4*)Wa;
        for (int i = tid; i < WSH / 8; i += 256) dst[i] = src[i];
    }
    {
        int4 z = {0, 0, 0, 0};
        int4* hz = (int4*)&hs[0][0];
        hz[tid] = z;
        hz[tid + 256] = z;
    }
    for (int i = tid; i < 64 * TT; i += 256) {     // 64 words' chars
        int w = perm[slot0 + i / TT];
        cs[i] = (unsigned short)(chars[w * TT + i % TT] * GSTR);
    }
    __syncthreads();

    int slotbase = slot0 + wv * 16;
    int word = perm[slotbase + n];
    int L = lens[word];
    int mL = L;                         // wave-max length (16-periodic lanes)
    #pragma unroll
    for (int off = 8; off; off >>= 1) {
        int t2 = __shfl_xor(mL, off);
        mL = mL > t2 ? mL : t2;
    }
    mL = __builtin_amdgcn_readfirstlane(mL);

    int pa0 = quad ^ x7;               // swizzled k-group, k 0..31
    int pa1 = (quad + 4) ^ x7;         // k 32..63

    const bf16x8* ap = (const bf16x8*)Wa;
    short* hw = hs[wv];
    const unsigned short* cw = cs + wv * 16 * TT + n * TT;
    const short* Gq = Gimg + d * GSH + quad * 4;

    float cst[TILES], hf[TILES];
    #pragma unroll
    for (int t = 0; t < TILES; ++t) { cst[t] = 0.0f; hf[t] = 0.0f; }

    int vcur = cw[(d && L > 0) ? (L - 1) : 0];   // pre-multiplied row offset

    #pragma unroll 1
    for (int s = 0; s < mL; ++s) {
        bool valid = s < L;

        bf16x8 B0 = *(const bf16x8*)(hw + n * 64 + pa0 * 8);  // h of step s-1
        bf16x8 B1 = *(const bf16x8*)(hw + n * 64 + pa1 * 8);

        int sn = s + 1;                 // prefetch next char offset
        int pn = (sn < L) ? (d ? (L - 1 - sn) : sn) : 0;
        int vnxt = cw[pn];

        const int2* gp = (const int2*)(Gq + vcur);   // 8B per tile, L2

        // pass 1: G-init + MFMAs (loads batched up front by unroll)
        f32x4 acc[TILES];
        #pragma unroll
        for (int tt = 0; tt < TILES; ++tt) {
            int2 gw = gp[tt * 4];       // tt*16 shorts = tt*4 int2
            f32x4 a;
            a[0] = bflo((unsigned)gw.x);  // gate i
            a[1] = bfhi((unsigned)gw.x);  // gate f
            a[2] = bflo((unsigned)gw.y);  // gate g
            a[3] = bfhi((unsigned)gw.y);  // gate o
            bf16x8 A0 = ap[(tt * 16 + n) * 8 + pa0];
            bf16x8 A1 = ap[(tt * 16 + n) * 8 + pa1];
            a = __builtin_amdgcn_mfma_f32_16x16x32_bf16(A0, B0, a, 0, 0, 0);
            a = __builtin_amdgcn_mfma_f32_16x16x32_bf16(A1, B1, a, 0, 0, 0);
            acc[tt] = a;
        }
        // pass 2: exp2-domain gates; h written back to wave-private LDS
        #pragma unroll
        for (int tt = 0; tt < TILES; ++tt) {
            float ig = frcp(1.0f + fexp2(acc[tt][0]));
            float fg = frcp(1.0f + fexp2(acc[tt][1]));
            float tg = 1.0f - 2.0f * frcp(1.0f + fexp2(acc[tt][2]));
            float og = frcp(1.0f + fexp2(acc[tt][3]));
            float cn = fg * cst[tt] + ig * tg;
            float hn = og * (1.0f - 2.0f * frcp(1.0f + fexp2(cn * P2LOG2E)));
            int uu = 4 * tt + quad;
            bool upd = valid && (uu < HH);
            cst[tt] = upd ? cn : cst[tt];
            hf[tt]  = upd ? hn : hf[tt];
            if (upd) {   // skipped when invalid -> h frozen (single buffer)
                int hidx = n * 64 + (((tt >> 1) ^ x7) << 3) + (tt & 1) * 4 + quad;
                hw[hidx] = f2bf(hn);
            }
        }
        vcur = vnxt;
    }

    float* orow = out + (size_t)word * (2 * HH) + d * HH;
    #pragma unroll
    for (int tt = 0; tt < TILES; ++tt) {
        int uu = 4 * tt + quad;
        if (uu < HH) orow[uu] = hf[tt];
    }
}

extern "C" void kernel_launch(void* const* d_in, const int* in_sizes, int n_in,
                              void* d_out, int out_size, void* d_ws, size_t ws_size,
                              hipStream_t stream) {
    const int*   chars = (const int*)d_in[0];
    const int*   lens  = (const int*)d_in[1];
    const float* emb   = (const float*)d_in[2];
    const float* Wih_f = (const float*)d_in[3];
    const float* Whh_f = (const float*)d_in[4];
    const float* bih_f = (const float*)d_in[5];
    const float* bhh_f = (const float*)d_in[6];
    const float* Wih_b = (const float*)d_in[7];
    const float* Whh_b = (const float*)d_in[8];
    const float* bih_b = (const float*)d_in[9];
    const float* bhh_b = (const float*)d_in[10];
    float* out = (float*)d_out;

    short* Gimg = (short*)d_ws;                 // 169600 B
    short* Wimg = Gimg + 2 * GSH;               //  53248 B
    int*   cnt  = (int*)(Wimg + 2 * WSH);       //  10752 B
    int*   perm = cnt + NB_H * 21;              // 131072 B   (total ~365 KB)

    k_prep<<<NB_G + NB_W + NB_H, 256, 0, stream>>>(emb, Wih_f, bih_f, bhh_f,
                                                   Wih_b, bih_b, bhh_b,
                                                   Whh_f, Whh_b, lens,
                                                   Gimg, Wimg, cnt);
    k_scat<<<NB_H, 256, 0, stream>>>(lens, cnt, perm);
    k_lstm<<<NBLK, 256, 0, stream>>>(chars, lens, perm, Gimg, Wimg, out);
}

// Round 9
// 179.017 us; speedup vs baseline: 1.7719x; 1.7719x over previous
//
#include <hip/hip_runtime.h>

// CharBiLSTMEmbedder: N=32768 words, T=20, E=H=50, V=200, out [N,100] fp32.
//
// Round-15: round-8's barrier-free structure was never really tested - it ran
// under forced spills. TOOLCHAIN RULE (2 data points: r1 (512,4)->VGPR 64 +
// 427MB scratch; r8 (256,4)->VGPR 64 + 440MB scratch; r0 (512,1)->VGPR 108
// no spill): launch_bounds 2nd arg >=4 makes the allocator squeeze to the
// 64-VGPR/8-wave budget and SPILL to get there. Fix: (256, 1).
//
// Structure (unchanged from r8): block = 4 INDEPENDENT waves; each wave owns
// one 16-word group x all 13 tiles; h is wave-private single-buffered LDS
// (same-wave in-order DS ops -> NO barrier in the step loop). Shared LDS:
// staged Whh A-image (26.6KB). 4 blocks/CU (LDS-capped) = 16 waves/CU.
// Carried: bf16 G from L2, pre-multiplied char offsets, exp2-domain gates,
// counting-sort LPT order, k_prep LDS-staged Wih, 3 plain launches.

#define TT    20
#define HH    50
#define VV    200
#define TILES 13        // 13*16 = 208 rows >= 200
#define GSTR  212       // G row stride in shorts (53 units * 4 gates)
#define GSH   (VV * GSTR)        // 42400 shorts per dir
#define WSH   (TILES * 16 * 64)  // 13312 shorts per dir
#define NW    32768
#define NB_G  50        // 2 dirs * 25 blocks of 8 emb rows
#define NB_W  104       // ceil(2*WSH/256)
#define NB_H  128       // 128*256 = 32768 words
#define NBLK  1024      // 2 dirs * 512 four-group clusters

#define N2LOG2E (-1.4426950408889634f)
#define P2LOG2E 2.8853900817779268f

typedef __attribute__((ext_vector_type(8))) short bf16x8;
typedef __attribute__((ext_vector_type(4))) float f32x4;

__device__ __forceinline__ float frcp(float x) { return __builtin_amdgcn_rcpf(x); }
#if __has_builtin(__builtin_amdgcn_exp2f)
__device__ __forceinline__ float fexp2(float x) { return __builtin_amdgcn_exp2f(x); }
#else
__device__ __forceinline__ float fexp2(float x) { return exp2f(x); }
#endif

__device__ __forceinline__ short f2bf(float x) {  // RNE fp32 -> bf16
    unsigned b = __builtin_bit_cast(unsigned, x);
    unsigned r = (b + 0x7FFFu + ((b >> 16) & 1u)) >> 16;
    return (short)r;
}
__device__ __forceinline__ float bfhi(unsigned w) {   // high bf16 of dword
    return __builtin_bit_cast(float, w & 0xFFFF0000u);
}
__device__ __forceinline__ float bflo(unsigned w) {   // low bf16 of dword
    return __builtin_bit_cast(float, w << 16);
}

// One kernel, three jobs by block range:
//  [0,NB_G): Gimg[d][v*GSTR+u*4+g] = bf16(sc_g*(emb'[v].W_ih[g*50+u]+b_ih+b_hh))
//            (Wih staged in LDS with sc folded; emb reads wave-uniform)
//  [NB_G,NB_G+NB_W): Wimg = MFMA A-operand image of sc_g*Whh (bf16, k-swizzled)
//  [NB_G+NB_W, +NB_H): cnt[block][21] = length histogram of 256 words
//  sc_g = -log2e for i,f,o rows; +2log2e for g rows (exp2-domain gates).
__global__ void k_prep(const float* __restrict__ emb,
                       const float* __restrict__ Wih_f, const float* __restrict__ bih_f,
                       const float* __restrict__ bhh_f,
                       const float* __restrict__ Wih_b, const float* __restrict__ bih_b,
                       const float* __restrict__ bhh_b,
                       const float* __restrict__ Whh_f, const float* __restrict__ Whh_b,
                       const int* __restrict__ lens,
                       short* __restrict__ Gimg, short* __restrict__ Wimg,
                       int* __restrict__ cnt) {
    int blk = blockIdx.x;
    int tid = threadIdx.x;
    __shared__ float Wl[4 * HH * HH];    // 200x50 f32, pre-scaled (40000 B)
    __shared__ float bs[4 * HH];         // (b_ih+b_hh)*sc

    if (blk < NB_G) {
        int d = blk / 25;
        int vbase = (blk % 25) * 8;
        const float* Wih = d ? Wih_b : Wih_f;
        const float* bih = d ? bih_b : bih_f;
        const float* bhh = d ? bhh_b : bhh_f;
        for (int i = tid; i < 4 * HH * HH; i += 256) {
            int r = i / HH;
            float sc = (r / HH == 2) ? P2LOG2E : N2LOG2E;
            Wl[i] = Wih[i] * sc;
        }
        if (tid < 4 * HH) {
            float sc = (tid / HH == 2) ? P2LOG2E : N2LOG2E;
            bs[tid] = (bih[tid] + bhh[tid]) * sc;
        }
        __syncthreads();
        int r = tid;                      // gate-row 0..199
        if (r < 4 * HH) {
            int g = r / HH, u = r % HH;
            #pragma unroll
            for (int vv = 0; vv < 8; ++vv) {
                int v = vbase + vv;
                float s = bs[r];
                if (v != 0) {             // PAD row of emb is zero
                    #pragma unroll 10
                    for (int e = 0; e < HH; ++e)
                        s = fmaf(emb[v * HH + e], Wl[r * HH + e], s);
                }
                Gimg[d * GSH + v * GSTR + u * 4 + g] = f2bf(s);
            }
        } else {                          // zero pad units u=50..52 (12 shorts/v)
            for (int k = r - 4 * HH; k < 8 * 12; k += 56) {
                int v = vbase + k / 12;
                Gimg[d * GSH + v * GSTR + 4 * HH + (k % 12)] = 0;
            }
        }
    } else if (blk < NB_G + NB_W) {
        int idx = (blk - NB_G) * 256 + tid;
        if (idx >= 2 * WSH) return;
        int d = idx / WSH;
        int e = idx % WSH;
        int t = e >> 10, m = (e >> 6) & 15, k = e & 63;
        int u = 4 * t + (m >> 2), g = m & 3;
        const float* Whh = d ? Whh_b : Whh_f;
        float sc = (g == 2) ? P2LOG2E : N2LOG2E;
        float val = (k < HH && u < HH) ? Whh[(g * HH + u) * HH + k] * sc : 0.0f;
        int ksw = (k & 7) | (((k >> 3) ^ (m & 7)) << 3);
        Wimg[d * WSH + (e & ~63) + ksw] = f2bf(val);
    } else {
        int hb = blk - NB_G - NB_W;      // 0..127
        __shared__ int hcnt[21];
        if (tid < 21) hcnt[tid] = 0;
        __syncthreads();
        atomicAdd(&hcnt[lens[hb * 256 + tid]], 1);
        __syncthreads();
        if (tid < 21) cnt[hb * 21 + tid] = hcnt[tid];
    }
}

// Merged scan+scatter: every block stages the 128x21 histogram into LDS,
// computes its own bucket offsets (buckets ordered L=20..0, LPT), scatters
// its 256 words.
__global__ void k_scat(const int* __restrict__ lens, const int* __restrict__ cnt,
                       int* __restrict__ perm) {
    __shared__ int lcnt[NB_H * 21];     // 10752 B
    __shared__ int part[8][21];
    __shared__ int tot[21];
    __shared__ int cur[21];
    int b = blockIdx.x, t = threadIdx.x;
    for (int i = t; i < NB_H * 21; i += 256) lcnt[i] = cnt[i];
    __syncthreads();
    if (t < 168) {
        int L = t % 21, c = t / 21;
        int s = 0;
        for (int bb = c * 16; bb < c * 16 + 16; ++bb) s += lcnt[bb * 21 + L];
        part[c][L] = s;
    }
    __syncthreads();
    if (t < 21) {
        int a = 0;
        #pragma unroll
        for (int c = 0; c < 8; ++c) a += part[c][t];
        tot[t] = a;
    }
    __syncthreads();
    if (t < 21) {
        int a = 0;
        for (int L2 = 20; L2 > t; --L2) a += tot[L2];   // start of bucket t
        for (int bb = 0; bb < b; ++bb) a += lcnt[bb * 21 + t];
        cur[t] = a;
    }
    __syncthreads();
    int i = b * 256 + t;
    int pos = atomicAdd(&cur[lens[i]], 1);
    perm[pos] = i;
}

// Block = 4 INDEPENDENT waves; each wave = one 16-word group x all 13 tiles.
// h wave-private single-buffered LDS (in-order same-wave DS => no barrier).
// A-image shared in LDS (read-only after staging). G bf16 from L2 per step.
// launch_bounds 2nd arg = 1: let the allocator take ~110 VGPR (do NOT squeeze).
__launch_bounds__(256, 1)
__global__ void k_lstm(const int* __restrict__ chars, const int* __restrict__ lens,
                       const int* __restrict__ perm,
                       const short* __restrict__ Gimg, const short* __restrict__ Wimg,
                       float* __restrict__ out) {
    __shared__ __align__(16) short Wa[WSH];        // 26624 B (one dir A-image)
    __shared__ __align__(16) short hs[4][1024];    // 8192 B wave-private h
    __shared__ unsigned short cs[4 * 16 * TT];     // 2560 B char*GSTR offsets

    int gb   = blockIdx.x;             // 0..1023, LPT (longest clusters first)
    int d    = gb & 1;
    int g4   = gb >> 1;                // 0..511: cluster of 4 sorted groups
    int slot0 = g4 * 64;
    int tid  = threadIdx.x;            // 0..255
    int lane = tid & 63;
    int wv   = __builtin_amdgcn_readfirstlane(tid >> 6);   // 0..3
    int quad = lane >> 4;
    int n    = lane & 15;
    int x7   = n & 7;

    // ---- stage (the only barrier in the kernel is after this) ----
    {
        const int4* src = (const int4*)(Wimg + d * WSH);
        int4* dst = (int4*)Wa;
        for (int i = tid; i < WSH / 8; i += 256) dst[i] = src[i];
    }
    {
        int4 z = {0, 0, 0, 0};
        int4* hz = (int4*)&hs[0][0];
        hz[tid] = z;
        hz[tid + 256] = z;
    }
    for (int i = tid; i < 64 * TT; i += 256) {     // 64 words' chars
        int w = perm[slot0 + i / TT];
        cs[i] = (unsigned short)(chars[w * TT + i % TT] * GSTR);
    }
    __syncthreads();

    int slotbase = slot0 + wv * 16;
    int word = perm[slotbase + n];
    int L = lens[word];
    int mL = L;                         // wave-max length (16-periodic lanes)
    #pragma unroll
    for (int off = 8; off; off >>= 1) {
        int t2 = __shfl_xor(mL, off);
        mL = mL > t2 ? mL : t2;
    }
    mL = __builtin_amdgcn_readfirstlane(mL);

    int pa0 = quad ^ x7;               // swizzled k-group, k 0..31
    int pa1 = (quad + 4) ^ x7;         // k 32..63

    const bf16x8* ap = (const bf16x8*)Wa;
    short* hw = hs[wv];
    const unsigned short* cw = cs + wv * 16 * TT + n * TT;
    const short* Gq = Gimg + d * GSH + quad * 4;

    float cst[TILES], hf[TILES];
    #pragma unroll
    for (int t = 0; t < TILES; ++t) { cst[t] = 0.0f; hf[t] = 0.0f; }

    int vcur = cw[(d && L > 0) ? (L - 1) : 0];   // pre-multiplied row offset

    #pragma unroll 1
    for (int s = 0; s < mL; ++s) {
        bool valid = s < L;

        bf16x8 B0 = *(const bf16x8*)(hw + n * 64 + pa0 * 8);  // h of step s-1
        bf16x8 B1 = *(const bf16x8*)(hw + n * 64 + pa1 * 8);

        int sn = s + 1;                 // prefetch next char offset
        int pn = (sn < L) ? (d ? (L - 1 - sn) : sn) : 0;
        int vnxt = cw[pn];

        const int2* gp = (const int2*)(Gq + vcur);   // 8B per tile, L2

        // pass 1: G-init + MFMAs (loads batched up front by unroll)
        f32x4 acc[TILES];
        #pragma unroll
        for (int tt = 0; tt < TILES; ++tt) {
            int2 gw = gp[tt * 4];       // tt*16 shorts = tt*4 int2
            f32x4 a;
            a[0] = bflo((unsigned)gw.x);  // gate i
            a[1] = bfhi((unsigned)gw.x);  // gate f
            a[2] = bflo((unsigned)gw.y);  // gate g
            a[3] = bfhi((unsigned)gw.y);  // gate o
            bf16x8 A0 = ap[(tt * 16 + n) * 8 + pa0];
            bf16x8 A1 = ap[(tt * 16 + n) * 8 + pa1];
            a = __builtin_amdgcn_mfma_f32_16x16x32_bf16(A0, B0, a, 0, 0, 0);
            a = __builtin_amdgcn_mfma_f32_16x16x32_bf16(A1, B1, a, 0, 0, 0);
            acc[tt] = a;
        }
        // pass 2: exp2-domain gates; h written back to wave-private LDS
        #pragma unroll
        for (int tt = 0; tt < TILES; ++tt) {
            float ig = frcp(1.0f + fexp2(acc[tt][0]));
            float fg = frcp(1.0f + fexp2(acc[tt][1]));
            float tg = 1.0f - 2.0f * frcp(1.0f + fexp2(acc[tt][2]));
            float og = frcp(1.0f + fexp2(acc[tt][3]));
            float cn = fg * cst[tt] + ig * tg;
            float hn = og * (1.0f - 2.0f * frcp(1.0f + fexp2(cn * P2LOG2E)));
            int uu = 4 * tt + quad;
            bool upd = valid && (uu < HH);
            cst[tt] = upd ? cn : cst[tt];
            hf[tt]  = upd ? hn : hf[tt];
            if (upd) {   // skipped when invalid -> h frozen (single buffer)
                int hidx = n * 64 + (((tt >> 1) ^ x7) << 3) + (tt & 1) * 4 + quad;
                hw[hidx] = f2bf(hn);
            }
        }
        vcur = vnxt;
    }

    float* orow = out + (size_t)word * (2 * HH) + d * HH;
    #pragma unroll
    for (int tt = 0; tt < TILES; ++tt) {
        int uu = 4 * tt + quad;
        if (uu < HH) orow[uu] = hf[tt];
    }
}

extern "C" void kernel_launch(void* const* d_in, const int* in_sizes, int n_in,
                              void* d_out, int out_size, void* d_ws, size_t ws_size,
                              hipStream_t stream) {
    const int*   chars = (const int*)d_in[0];
    const int*   lens  = (const int*)d_in[1];
    const float* emb   = (const float*)d_in[2];
    const float* Wih_f = (const float*)d_in[3];
    const float* Whh_f = (const float*)d_in[4];
    const float* bih_f = (const float*)d_in[5];
    const float* bhh_f = (const float*)d_in[6];
    const float* Wih_b = (const float*)d_in[7];
    const float* Whh_b = (const float*)d_in[8];
    const float* bih_b = (const float*)d_in[9];
    const float* bhh_b = (const float*)d_in[10];
    float* out = (float*)d_out;

    short* Gimg = (short*)d_ws;                 // 169600 B
    short* Wimg = Gimg + 2 * GSH;               //  53248 B
    int*   cnt  = (int*)(Wimg + 2 * WSH);       //  10752 B
    int*   perm = cnt + NB_H * 21;              // 131072 B   (total ~365 KB)

    k_prep<<<NB_G + NB_W + NB_H, 256, 0, stream>>>(emb, Wih_f, bih_f, bhh_f,
                                                   Wih_b, bih_b, bhh_b,
                                                   Whh_f, Whh_b, lens,
                                                   Gimg, Wimg, cnt);
    k_scat<<<NB_H, 256, 0, stream>>>(lens, cnt, perm);
    k_lstm<<<NBLK, 256, 0, stream>>>(chars, lens, perm, Gimg, Wimg, out);
}